// Round 4
// baseline (180.635 us; speedup 1.0000x reference)
//
#include <hip/hip_runtime.h>
#include <math.h>

#define B_ 32
#define N_ 512
#define F_ 1024
#define EPS 1e-6f

typedef _Float16 h8v __attribute__((ext_vector_type(8)));
typedef _Float16 h4v __attribute__((ext_vector_type(4)));
typedef float    f4v __attribute__((ext_vector_type(4)));

__device__ __forceinline__ void gl_lds16(const void* g, void* l) {
    __builtin_amdgcn_global_load_lds(
        (const __attribute__((address_space(1))) unsigned int*)g,
        (__attribute__((address_space(3))) unsigned int*)l, 16, 0, 0);
}

// ---------------------------------------------------------------------------
// Kernel A: per-row sum/sumsq + x -> fp16. One wave per row.
// ---------------------------------------------------------------------------
__global__ __launch_bounds__(256) void rowsumcvt_kernel(const float* __restrict__ x,
                                                        float* __restrict__ sq,
                                                        float* __restrict__ s,
                                                        _Float16* __restrict__ xh) {
    int row  = blockIdx.x * 4 + (threadIdx.x >> 6);
    int lane = threadIdx.x & 63;
    const float4* xr = (const float4*)(x + (size_t)row * F_);
    float a1 = 0.f, a2 = 0.f;
#pragma unroll
    for (int it = 0; it < 4; ++it) {
        float4 v = xr[lane + it * 64];
        a1 += v.x + v.y + v.z + v.w;
        a2 += v.x * v.x + v.y * v.y + v.z * v.z + v.w * v.w;
        h4v h;
        h[0] = (_Float16)v.x; h[1] = (_Float16)v.y;
        h[2] = (_Float16)v.z; h[3] = (_Float16)v.w;
        *(h4v*)&xh[(size_t)row * F_ + (size_t)(lane + it * 64) * 4] = h;
    }
#pragma unroll
    for (int off = 32; off > 0; off >>= 1) {
        a1 += __shfl_xor(a1, off);
        a2 += __shfl_xor(a2, off);
    }
    if (lane == 0) { s[row] = a1; sq[row] = a2; }
}

// W -> fp16
__global__ __launch_bounds__(256) void wcvt_kernel(const float* __restrict__ W,
                                                   _Float16* __restrict__ Wh) {
    size_t e = ((size_t)blockIdx.x * 256 + threadIdx.x) * 4;
    float4 v = *(const float4*)(W + e);
    h4v h;
    h[0] = (_Float16)v.x; h[1] = (_Float16)v.y;
    h[2] = (_Float16)v.z; h[3] = (_Float16)v.w;
    *(h4v*)&Wh[e] = h;
}

// ---------------------------------------------------------------------------
// Kernel B: dist GEMM, 128(i)x64(j) tile, BK=32, 256 thr (4 waves, 2x2,
// wave-tile 64x32). Epilogue: d = sqrt(...), per-column (128-row chunk)
// max+sumexp partials -> pm/pl[ic][B][N], and E = exp(d - m_chunk) in fp16.
// Grid (8,4,32) = 1024 blocks -> 4 blocks/CU.
// ---------------------------------------------------------------------------
__global__ __launch_bounds__(256, 4) void dist_mfma(const _Float16* __restrict__ xh,
                                                    const float* __restrict__ sq,
                                                    const float* __restrict__ s,
                                                    _Float16* __restrict__ Eb,
                                                    float* __restrict__ pm,
                                                    float* __restrict__ pl) {
    const int b  = blockIdx.z;
    const int i0 = blockIdx.y * 128;
    const int j0 = blockIdx.x * 64;

    __shared__ __align__(16) _Float16 Ah[128 * 32];
    __shared__ __align__(16) _Float16 Bh[64 * 32];
    __shared__ float sm_m[2][64];
    __shared__ float sm_s[2][64];
    __shared__ float sm_c[64];

    const int tid  = threadIdx.x;
    const int lane = tid & 63;
    const int w    = tid >> 6;
    const int iw   = (w >> 1) * 64;   // wave i-offset
    const int jw   = (w & 1) * 32;    // wave j-offset
    const int fr   = lane & 15;
    const int fk   = (lane >> 4) * 8;
    const int q4   = (lane >> 4) * 4;

    const int srow = tid >> 2;           // 0..63
    const int scol = (tid & 3) * 8;
    const size_t aBase = ((size_t)(b * N_ + i0 + srow)) * F_ + scol;
    const size_t bBase = ((size_t)(b * N_ + j0 + srow)) * F_ + scol;

    f4v acc[4][2] = {};

    for (int k0 = 0; k0 < F_; k0 += 32) {
        gl_lds16(xh + aBase + k0, &Ah[tid * 8]);
        gl_lds16(xh + aBase + (size_t)64 * F_ + k0, &Ah[2048 + tid * 8]);
        gl_lds16(xh + bBase + k0, &Bh[tid * 8]);
        __syncthreads();

        h8v a[4], bb[2];
#pragma unroll
        for (int mi = 0; mi < 4; ++mi) a[mi]  = *(const h8v*)&Ah[(iw + mi * 16 + fr) * 32 + fk];
#pragma unroll
        for (int ni = 0; ni < 2; ++ni) bb[ni] = *(const h8v*)&Bh[(jw + ni * 16 + fr) * 32 + fk];
#pragma unroll
        for (int mi = 0; mi < 4; ++mi)
#pragma unroll
            for (int ni = 0; ni < 2; ++ni)
                acc[mi][ni] = __builtin_amdgcn_mfma_f32_16x16x32_f16(a[mi], bb[ni], acc[mi][ni], 0, 0, 0);

        __syncthreads();
    }

    // epilogue 1: acc -> dist values
    float sqj[2], sj[2];
#pragma unroll
    for (int ni = 0; ni < 2; ++ni) {
        int j = j0 + jw + ni * 16 + fr;
        sqj[ni] = sq[b * N_ + j];
        sj[ni]  = s [b * N_ + j];
    }
#pragma unroll
    for (int mi = 0; mi < 4; ++mi)
#pragma unroll
        for (int r = 0; r < 4; ++r) {
            int i = i0 + iw + mi * 16 + q4 + r;
            float sqi = sq[b * N_ + i];
            float si  = s [b * N_ + i];
#pragma unroll
            for (int ni = 0; ni < 2; ++ni) {
                int j = j0 + jw + ni * 16 + fr;
                float d2 = sqi + sqj[ni] - 2.f * acc[mi][ni][r]
                         + 2.f * EPS * (si - sj[ni]) + (float)F_ * EPS * EPS;
                float dd = (i == j) ? 0.f : sqrtf(fmaxf(d2, 0.f));
                acc[mi][ni][r] = dd;
            }
        }

    // epilogue 2: per-column stats over the tile's 128 rows
#pragma unroll
    for (int ni = 0; ni < 2; ++ni) {
        float m_l = -1e30f;
#pragma unroll
        for (int mi = 0; mi < 4; ++mi)
#pragma unroll
            for (int r = 0; r < 4; ++r) m_l = fmaxf(m_l, acc[mi][ni][r]);
        float s_l = 0.f;
#pragma unroll
        for (int mi = 0; mi < 4; ++mi)
#pragma unroll
            for (int r = 0; r < 4; ++r) s_l += __expf(acc[mi][ni][r] - m_l);
#pragma unroll
        for (int off = 16; off < 64; off <<= 1) {
            float m_o = __shfl_xor(m_l, off);
            float s_o = __shfl_xor(s_l, off);
            float nm  = fmaxf(m_l, m_o);
            s_l = s_l * __expf(m_l - nm) + s_o * __expf(m_o - nm);
            m_l = nm;
        }
        if (lane < 16) {
            sm_m[w >> 1][jw + ni * 16 + lane] = m_l;
            sm_s[w >> 1][jw + ni * 16 + lane] = s_l;
        }
    }
    __syncthreads();
    if (tid < 64) {
        float m0 = sm_m[0][tid], m1 = sm_m[1][tid];
        float mm = fmaxf(m0, m1);
        float ss = sm_s[0][tid] * __expf(m0 - mm) + sm_s[1][tid] * __expf(m1 - mm);
        size_t o = ((size_t)blockIdx.y * B_ + b) * N_ + j0 + tid;
        pm[o] = mm;
        pl[o] = ss;
        sm_c[tid] = mm;
    }
    __syncthreads();

    // epilogue 3: E = exp(d - m_chunk) -> fp16
#pragma unroll
    for (int ni = 0; ni < 2; ++ni) {
        float mc = sm_c[jw + ni * 16 + fr];
        int j = j0 + jw + ni * 16 + fr;
#pragma unroll
        for (int mi = 0; mi < 4; ++mi)
#pragma unroll
            for (int r = 0; r < 4; ++r) {
                int i = i0 + iw + mi * 16 + q4 + r;
                Eb[((size_t)(b * N_ + i)) * N_ + j] = (_Float16)__expf(acc[mi][ni][r] - mc);
            }
    }
}

// ---------------------------------------------------------------------------
// Kernel C: out = (E . alpha_j) @ W^T. 128(i)x64(k) tile, BK=32, 4 waves.
// alpha[j] = exp(pm[ic][j] - m_j) / l_j computed per block (ic = i-tile),
// folded into the W-side fragments. Grid (8,4,32) = 1024 blocks.
// ---------------------------------------------------------------------------
__global__ __launch_bounds__(256, 4) void out_mfma(const _Float16* __restrict__ Eb,
                                                   const _Float16* __restrict__ Wh,
                                                   const float* __restrict__ pm,
                                                   const float* __restrict__ pl,
                                                   float* __restrict__ out) {
    const int b  = blockIdx.z;
    const int i0 = blockIdx.y * 128;
    const int k0 = blockIdx.x * 64;
    const int ic = blockIdx.y;

    __shared__ __align__(16) _Float16 As[128 * 32];
    __shared__ __align__(16) _Float16 Bs[64 * 32];
    __shared__ __align__(16) _Float16 af[N_];

    const int tid  = threadIdx.x;
    const int lane = tid & 63;
    const int w    = tid >> 6;
    const int iw   = (w >> 1) * 64;
    const int kw   = (w & 1) * 32;
    const int fr   = lane & 15;
    const int fk   = (lane >> 4) * 8;
    const int q4   = (lane >> 4) * 4;

    // alpha table
    for (int j = tid; j < N_; j += 256) {
        float mx = -1e30f;
#pragma unroll
        for (int c = 0; c < 4; ++c) mx = fmaxf(mx, pm[((size_t)c * B_ + b) * N_ + j]);
        float l = 0.f;
#pragma unroll
        for (int c = 0; c < 4; ++c)
            l += pl[((size_t)c * B_ + b) * N_ + j] * __expf(pm[((size_t)c * B_ + b) * N_ + j] - mx);
        af[j] = (_Float16)(__expf(pm[((size_t)ic * B_ + b) * N_ + j] - mx) / l);
    }

    const int srow = tid >> 2;
    const int scol = (tid & 3) * 8;
    const size_t aBase = ((size_t)(b * N_ + i0 + srow)) * N_ + scol;
    const size_t bBase = ((size_t)(k0 + srow)) * N_ + scol;

    f4v acc[4][2] = {};

    for (int j0 = 0; j0 < N_; j0 += 32) {
        gl_lds16(Eb + aBase + j0, &As[tid * 8]);
        gl_lds16(Eb + aBase + (size_t)64 * N_ + j0, &As[2048 + tid * 8]);
        gl_lds16(Wh + bBase + j0, &Bs[tid * 8]);
        __syncthreads();

        h8v a[4], bb[2];
        h8v al = *(const h8v*)&af[j0 + fk];
#pragma unroll
        for (int mi = 0; mi < 4; ++mi) a[mi]  = *(const h8v*)&As[(iw + mi * 16 + fr) * 32 + fk];
#pragma unroll
        for (int ni = 0; ni < 2; ++ni) bb[ni] = *(const h8v*)&Bs[(kw + ni * 16 + fr) * 32 + fk] * al;
#pragma unroll
        for (int mi = 0; mi < 4; ++mi)
#pragma unroll
            for (int ni = 0; ni < 2; ++ni)
                acc[mi][ni] = __builtin_amdgcn_mfma_f32_16x16x32_f16(a[mi], bb[ni], acc[mi][ni], 0, 0, 0);

        __syncthreads();
    }

#pragma unroll
    for (int mi = 0; mi < 4; ++mi)
#pragma unroll
        for (int r = 0; r < 4; ++r) {
            int i = i0 + iw + mi * 16 + q4 + r;
#pragma unroll
            for (int ni = 0; ni < 2; ++ni) {
                int k = k0 + kw + ni * 16 + fr;
                out[((size_t)(b * N_ + i)) * N_ + k] = acc[mi][ni][r];
            }
        }
}

// ---------------------------------------------------------------------------
extern "C" void kernel_launch(void* const* d_in, const int* in_sizes, int n_in,
                              void* d_out, int out_size, void* d_ws, size_t ws_size,
                              hipStream_t stream) {
    const float* x = (const float*)d_in[0];
    const float* W = (const float*)d_in[1];
    float* out = (float*)d_out;

    const size_t NN  = (size_t)B_ * N_ * N_;       // 8.39M elements
    const size_t NFh = (size_t)B_ * N_ * F_ / 2;   // fp16 x in float slots

    float*    ws = (float*)d_ws;
    _Float16* Eb = (_Float16*)ws;                   // B*N*N fp16   (NN/2 float slots)
    _Float16* xh = (_Float16*)(ws + NN / 2);        // B*N*F fp16
    _Float16* Wh = (_Float16*)(ws + NN / 2 + NFh);  // N*N fp16
    float*    sq = ws + NN / 2 + NFh + (size_t)N_ * N_ / 2;
    float*    s  = sq + (size_t)B_ * N_;
    float*    pm = s  + (size_t)B_ * N_;            // 4*B*N
    float*    pl = pm + (size_t)4 * B_ * N_;        // 4*B*N

    rowsumcvt_kernel<<<B_ * N_ / 4, 256, 0, stream>>>(x, sq, s, xh);
    wcvt_kernel<<<N_ * N_ / 1024, 256, 0, stream>>>(W, Wh);
    dist_mfma<<<dim3(N_ / 64, N_ / 128, B_), 256, 0, stream>>>(xh, sq, s, Eb, pm, pl);
    out_mfma<<<dim3(N_ / 64, N_ / 128, B_), 256, 0, stream>>>(Eb, Wh, pm, pl, out);
}

// Round 5
// 155.089 us; speedup vs baseline: 1.1647x; 1.1647x over previous
//
#include <hip/hip_runtime.h>
#include <math.h>

#define B_ 32
#define N_ 512
#define F_ 1024
#define EPS 1e-6f

typedef _Float16 h8v __attribute__((ext_vector_type(8)));
typedef _Float16 h4v __attribute__((ext_vector_type(4)));
typedef float    f4v __attribute__((ext_vector_type(4)));

__device__ __forceinline__ void gl_lds16(const void* g, void* l) {
    __builtin_amdgcn_global_load_lds(
        (const __attribute__((address_space(1))) unsigned int*)g,
        (__attribute__((address_space(3))) unsigned int*)l, 16, 0, 0);
}

// ---------------------------------------------------------------------------
// Kernel A (merged): blocks 0..4095 -> per-row sum/sumsq + x->fp16 (one wave
// per row); blocks 4096..4351 -> W->fp16.
// ---------------------------------------------------------------------------
__global__ __launch_bounds__(256) void prep_kernel(const float* __restrict__ x,
                                                   const float* __restrict__ W,
                                                   float* __restrict__ sq,
                                                   float* __restrict__ s,
                                                   _Float16* __restrict__ xh,
                                                   _Float16* __restrict__ Wh) {
    const int bid = blockIdx.x;
    if (bid < 4096) {
        int row  = bid * 4 + (threadIdx.x >> 6);
        int lane = threadIdx.x & 63;
        const float4* xr = (const float4*)(x + (size_t)row * F_);
        float a1 = 0.f, a2 = 0.f;
#pragma unroll
        for (int it = 0; it < 4; ++it) {
            float4 v = xr[lane + it * 64];
            a1 += v.x + v.y + v.z + v.w;
            a2 += v.x * v.x + v.y * v.y + v.z * v.z + v.w * v.w;
            h4v h;
            h[0] = (_Float16)v.x; h[1] = (_Float16)v.y;
            h[2] = (_Float16)v.z; h[3] = (_Float16)v.w;
            *(h4v*)&xh[(size_t)row * F_ + (size_t)(lane + it * 64) * 4] = h;
        }
#pragma unroll
        for (int off = 32; off > 0; off >>= 1) {
            a1 += __shfl_xor(a1, off);
            a2 += __shfl_xor(a2, off);
        }
        if (lane == 0) { s[row] = a1; sq[row] = a2; }
    } else {
        size_t e = ((size_t)(bid - 4096) * 256 + threadIdx.x) * 4;
        float4 v = *(const float4*)(W + e);
        h4v h;
        h[0] = (_Float16)v.x; h[1] = (_Float16)v.y;
        h[2] = (_Float16)v.z; h[3] = (_Float16)v.w;
        *(h4v*)&Wh[e] = h;
    }
}

// ---------------------------------------------------------------------------
// Kernel B: dist GEMM 128x128 tile, BK=64, XOR-swizzled LDS (conflict-free
// frag reads), 4 waves each 64x64. Epilogue: d=sqrt(...), fused per-column
// (128-row chunk) max+sumexp -> pm/pl[ic=4][B][N], E = exp(d - m_chunk) fp16.
// Grid (4,4,32) = 512 blocks (2/CU, grid-capped).
// LDS swizzle: chunk-of-8 position cs stores global chunk c8 = cs ^ (row&7).
// ---------------------------------------------------------------------------
__global__ __launch_bounds__(256) void dist_mfma(const _Float16* __restrict__ xh,
                                                 const float* __restrict__ sq,
                                                 const float* __restrict__ s,
                                                 _Float16* __restrict__ Eb,
                                                 float* __restrict__ pm,
                                                 float* __restrict__ pl) {
    const int b  = blockIdx.z;
    const int i0 = blockIdx.y * 128;
    const int j0 = blockIdx.x * 128;

    __shared__ __align__(16) _Float16 Ah[128 * 64];
    __shared__ __align__(16) _Float16 Bh[128 * 64];
    __shared__ float sm_m[2][128];
    __shared__ float sm_s[2][128];
    __shared__ float sm_c[128];

    const int tid  = threadIdx.x;
    const int lane = tid & 63;
    const int w    = tid >> 6;
    const int im   = (w >> 1) * 64;
    const int jn   = (w & 1) * 64;
    const int fr   = lane & 15;
    const int kq   = lane >> 4;      // 0..3
    const int q4   = kq * 4;

    // staging addresses (swizzled global source -> contiguous LDS dest)
    size_t aOff[4], bOff[4];
    int    lOff[4];
#pragma unroll
    for (int it = 0; it < 4; ++it) {
        int flat = it * 256 + tid;       // chunk id: tile = 128 rows x 8 chunks
        int row  = flat >> 3;
        int c8   = (flat & 7) ^ (row & 7);
        aOff[it] = ((size_t)(b * N_ + i0 + row)) * F_ + c8 * 8;
        bOff[it] = ((size_t)(b * N_ + j0 + row)) * F_ + c8 * 8;
        lOff[it] = flat * 8;
    }

    f4v acc[4][4] = {};

    for (int k0 = 0; k0 < F_; k0 += 64) {
#pragma unroll
        for (int it = 0; it < 4; ++it) {
            gl_lds16(xh + aOff[it] + k0, &Ah[lOff[it]]);
            gl_lds16(xh + bOff[it] + k0, &Bh[lOff[it]]);
        }
        __syncthreads();

#pragma unroll
        for (int kf = 0; kf < 2; ++kf) {
            h8v a[4], bb[4];
#pragma unroll
            for (int mi = 0; mi < 4; ++mi) {
                int r = im + mi * 16 + fr;
                a[mi] = *(const h8v*)&Ah[r * 64 + (((kf << 2) | kq) ^ (r & 7)) * 8];
            }
#pragma unroll
            for (int ni = 0; ni < 4; ++ni) {
                int r = jn + ni * 16 + fr;
                bb[ni] = *(const h8v*)&Bh[r * 64 + (((kf << 2) | kq) ^ (r & 7)) * 8];
            }
#pragma unroll
            for (int mi = 0; mi < 4; ++mi)
#pragma unroll
                for (int ni = 0; ni < 4; ++ni)
                    acc[mi][ni] = __builtin_amdgcn_mfma_f32_16x16x32_f16(a[mi], bb[ni], acc[mi][ni], 0, 0, 0);
        }
        __syncthreads();
    }

    // epilogue 1: acc -> dist values
    float sqj[4], sj[4];
#pragma unroll
    for (int ni = 0; ni < 4; ++ni) {
        int j = j0 + jn + ni * 16 + fr;
        sqj[ni] = sq[b * N_ + j];
        sj[ni]  = s [b * N_ + j];
    }
#pragma unroll
    for (int mi = 0; mi < 4; ++mi)
#pragma unroll
        for (int r = 0; r < 4; ++r) {
            int i = i0 + im + mi * 16 + q4 + r;
            float sqi = sq[b * N_ + i];
            float si  = s [b * N_ + i];
#pragma unroll
            for (int ni = 0; ni < 4; ++ni) {
                int j = j0 + jn + ni * 16 + fr;
                float d2 = sqi + sqj[ni] - 2.f * acc[mi][ni][r]
                         + 2.f * EPS * (si - sj[ni]) + (float)F_ * EPS * EPS;
                float dd = (i == j) ? 0.f : sqrtf(fmaxf(d2, 0.f));
                acc[mi][ni][r] = dd;
            }
        }

    // epilogue 2: per-column stats over this tile's 128 rows
#pragma unroll
    for (int ni = 0; ni < 4; ++ni) {
        float m_l = -1e30f;
#pragma unroll
        for (int mi = 0; mi < 4; ++mi)
#pragma unroll
            for (int r = 0; r < 4; ++r) m_l = fmaxf(m_l, acc[mi][ni][r]);
        float s_l = 0.f;
#pragma unroll
        for (int mi = 0; mi < 4; ++mi)
#pragma unroll
            for (int r = 0; r < 4; ++r) s_l += __expf(acc[mi][ni][r] - m_l);
#pragma unroll
        for (int off = 16; off < 64; off <<= 1) {
            float m_o = __shfl_xor(m_l, off);
            float s_o = __shfl_xor(s_l, off);
            float nm  = fmaxf(m_l, m_o);
            s_l = s_l * __expf(m_l - nm) + s_o * __expf(m_o - nm);
            m_l = nm;
        }
        if (lane < 16) {
            sm_m[w >> 1][jn + ni * 16 + lane] = m_l;
            sm_s[w >> 1][jn + ni * 16 + lane] = s_l;
        }
    }
    __syncthreads();
    if (tid < 128) {
        float m0 = sm_m[0][tid], m1 = sm_m[1][tid];
        float mm = fmaxf(m0, m1);
        float ss = sm_s[0][tid] * __expf(m0 - mm) + sm_s[1][tid] * __expf(m1 - mm);
        size_t o = ((size_t)blockIdx.y * B_ + b) * N_ + j0 + tid;
        pm[o] = mm;
        pl[o] = ss;
        sm_c[tid] = mm;
    }
    __syncthreads();

    // epilogue 3: E = exp(d - m_chunk) -> fp16
#pragma unroll
    for (int ni = 0; ni < 4; ++ni) {
        float mc = sm_c[jn + ni * 16 + fr];
        int j = j0 + jn + ni * 16 + fr;
#pragma unroll
        for (int mi = 0; mi < 4; ++mi)
#pragma unroll
            for (int r = 0; r < 4; ++r) {
                int i = i0 + im + mi * 16 + q4 + r;
                Eb[((size_t)(b * N_ + i)) * N_ + j] = (_Float16)__expf(acc[mi][ni][r] - mc);
            }
    }
}

// ---------------------------------------------------------------------------
// Kernel C: out = (E . alpha_j) @ W^T. 128x128 tile, BK=64, swizzled LDS.
// alpha[j] = exp(pm[ic][j] - m_j)/l_j, ic = blockIdx.y (E's i-chunk), folded
// into the W-side fragments as fp16. Grid (4,4,32) = 512 blocks.
// ---------------------------------------------------------------------------
__global__ __launch_bounds__(256) void out_mfma(const _Float16* __restrict__ Eb,
                                                const _Float16* __restrict__ Wh,
                                                const float* __restrict__ pm,
                                                const float* __restrict__ pl,
                                                float* __restrict__ out) {
    const int b  = blockIdx.z;
    const int i0 = blockIdx.y * 128;
    const int k0 = blockIdx.x * 128;
    const int ic = blockIdx.y;

    __shared__ __align__(16) _Float16 As[128 * 64];
    __shared__ __align__(16) _Float16 Bs[128 * 64];
    __shared__ __align__(16) _Float16 af[N_];

    const int tid  = threadIdx.x;
    const int lane = tid & 63;
    const int w    = tid >> 6;
    const int im   = (w >> 1) * 64;
    const int kn   = (w & 1) * 64;
    const int fr   = lane & 15;
    const int kq   = lane >> 4;
    const int fk   = kq * 8;
    const int q4   = kq * 4;

    // alpha table (512 j, 2 per thread)
    for (int j = tid; j < N_; j += 256) {
        float mx = -1e30f;
#pragma unroll
        for (int c = 0; c < 4; ++c) mx = fmaxf(mx, pm[((size_t)c * B_ + b) * N_ + j]);
        float l = 0.f;
#pragma unroll
        for (int c = 0; c < 4; ++c)
            l += pl[((size_t)c * B_ + b) * N_ + j] * __expf(pm[((size_t)c * B_ + b) * N_ + j] - mx);
        af[j] = (_Float16)(__expf(pm[((size_t)ic * B_ + b) * N_ + j] - mx) / l);
    }

    size_t aOff[4], bOff[4];
    int    lOff[4];
#pragma unroll
    for (int it = 0; it < 4; ++it) {
        int flat = it * 256 + tid;
        int row  = flat >> 3;
        int c8   = (flat & 7) ^ (row & 7);
        aOff[it] = ((size_t)(b * N_ + i0 + row)) * N_ + c8 * 8;
        bOff[it] = ((size_t)(k0 + row)) * N_ + c8 * 8;
        lOff[it] = flat * 8;
    }

    f4v acc[4][4] = {};

    for (int j0 = 0; j0 < N_; j0 += 64) {
#pragma unroll
        for (int it = 0; it < 4; ++it) {
            gl_lds16(Eb + aOff[it] + j0, &As[lOff[it]]);
            gl_lds16(Wh + bOff[it] + j0, &Bs[lOff[it]]);
        }
        __syncthreads();   // also fences the af writes on first iteration

#pragma unroll
        for (int kf = 0; kf < 2; ++kf) {
            h8v a[4], bb[4];
            h8v al = *(const h8v*)&af[j0 + kf * 32 + fk];
#pragma unroll
            for (int mi = 0; mi < 4; ++mi) {
                int r = im + mi * 16 + fr;
                a[mi] = *(const h8v*)&As[r * 64 + (((kf << 2) | kq) ^ (r & 7)) * 8];
            }
#pragma unroll
            for (int ni = 0; ni < 4; ++ni) {
                int r = kn + ni * 16 + fr;
                bb[ni] = *(const h8v*)&Bs[r * 64 + (((kf << 2) | kq) ^ (r & 7)) * 8] * al;
            }
#pragma unroll
            for (int mi = 0; mi < 4; ++mi)
#pragma unroll
                for (int ni = 0; ni < 4; ++ni)
                    acc[mi][ni] = __builtin_amdgcn_mfma_f32_16x16x32_f16(a[mi], bb[ni], acc[mi][ni], 0, 0, 0);
        }
        __syncthreads();
    }

#pragma unroll
    for (int mi = 0; mi < 4; ++mi)
#pragma unroll
        for (int r = 0; r < 4; ++r) {
            int i = i0 + im + mi * 16 + q4 + r;
#pragma unroll
            for (int ni = 0; ni < 4; ++ni) {
                int k = k0 + kn + ni * 16 + fr;
                out[((size_t)(b * N_ + i)) * N_ + k] = acc[mi][ni][r];
            }
        }
}

// ---------------------------------------------------------------------------
extern "C" void kernel_launch(void* const* d_in, const int* in_sizes, int n_in,
                              void* d_out, int out_size, void* d_ws, size_t ws_size,
                              hipStream_t stream) {
    const float* x = (const float*)d_in[0];
    const float* W = (const float*)d_in[1];
    float* out = (float*)d_out;

    const size_t NN  = (size_t)B_ * N_ * N_;       // 8.39M elements
    const size_t NFh = (size_t)B_ * N_ * F_ / 2;   // fp16 x in float slots

    float*    ws = (float*)d_ws;
    _Float16* Eb = (_Float16*)ws;                   // B*N*N fp16
    _Float16* xh = (_Float16*)(ws + NN / 2);        // B*N*F fp16
    _Float16* Wh = (_Float16*)(ws + NN / 2 + NFh);  // N*N fp16
    float*    sq = ws + NN / 2 + NFh + (size_t)N_ * N_ / 2;
    float*    s  = sq + (size_t)B_ * N_;
    float*    pm = s  + (size_t)B_ * N_;            // 4*B*N
    float*    pl = pm + (size_t)4 * B_ * N_;        // 4*B*N

    prep_kernel<<<4096 + 256, 256, 0, stream>>>(x, W, sq, s, xh, Wh);
    dist_mfma<<<dim3(N_ / 128, N_ / 128, B_), 256, 0, stream>>>(xh, sq, s, Eb, pm, pl);
    out_mfma<<<dim3(N_ / 128, N_ / 128, B_), 256, 0, stream>>>(Eb, Wh, pm, pl, out);
}